// Round 4
// baseline (409.430 us; speedup 1.0000x reference)
//
#include <hip/hip_runtime.h>
#include <math.h>

// GCNConv QNet: out = tanh( (segsum(x[src]*norm, dst) + selfloop) @ W1 + b1 ) @ W2 + b2
// norm = dinv[src]*dinv[dst], dinv = rsqrt(in_degree + 1).
// Aggregation in 32-dim obs space (W1 applied AFTER segment_sum — linearity).
// R4: LDS multisplit by dst-bucket (no scattered 4B global writes), then
// per-bucket LDS aggregation (no global f32 atomics, no CSR, no scans).

#define NOBS 32
#define NMID 64
#define NACT 8
#define BSH 7
#define BNODES 128           // nodes per bucket
#define CAP 4096             // max entries per bucket (mean ~2048, +45 sigma)
#define ARENA_B 16384        // bytes per bucket arena (= CAP*4 = BNODES*NOBS*4)
#define SPLIT_E 4096         // edges per split block

// Detect whether edge_index arrived as int64 (reference dtype) or int32.
__device__ __forceinline__ bool edges_i64(const int* ei) {
    return (ei[1] | ei[3] | ei[5] | ei[7]) == 0;
}

__global__ void k_zero(int* __restrict__ p, int n) {
    int i = blockIdx.x * blockDim.x + threadIdx.x;
    if (i < n) p[i] = 0;
}

// Multisplit: group 4096 edges by bucket in LDS, flush contiguous runs.
__global__ __launch_bounds__(256) void k_split(
        const int* __restrict__ ei, int* __restrict__ gcnt,
        unsigned int* __restrict__ arena, long long e, int nbuckets) {
    __shared__ int ebuf[SPLIT_E];             // packed entries (16 KB)
    __shared__ unsigned short bbuf[SPLIT_E];  // bucket ids (8 KB)
    __shared__ int sbuf[SPLIT_E];             // bucket-grouped entries (16 KB)
    __shared__ int offs[1024];
    __shared__ int cur[1024];
    __shared__ int tsum[256];
    const int tid = threadIdx.x;

    for (int b = tid; b < 1024; b += 256) cur[b] = 0;  // cur = hist
    __syncthreads();

    const long long base = (long long)blockIdx.x * SPLIT_E;
    const bool i64 = edges_i64(ei);
    const long long* e64 = (const long long*)ei;
    for (int k = tid; k < SPLIT_E; k += 256) {
        long long ge = base + k;
        if (ge < e) {
            int s, d;
            if (i64) { s = (int)e64[ge]; d = (int)e64[e + ge]; }
            else     { s = ei[ge];       d = ei[e + ge]; }
            ebuf[k] = s | ((d & (BNODES - 1)) << 20);
            int b = d >> BSH;
            bbuf[k] = (unsigned short)b;
            atomicAdd(&cur[b], 1);
        } else {
            bbuf[k] = 0xFFFFu;
        }
    }
    __syncthreads();

    // exclusive scan of cur(=hist)[0..1024), 4 bins/thread
    const int t4 = tid * 4;
    int s0 = cur[t4], s1 = cur[t4 + 1], s2 = cur[t4 + 2], s3 = cur[t4 + 3];
    int my = s0 + s1 + s2 + s3;
    tsum[tid] = my;
    __syncthreads();
    for (int off = 1; off < 256; off <<= 1) {
        int t = (tid >= off) ? tsum[tid - off] : 0;
        __syncthreads();
        tsum[tid] += t;
        __syncthreads();
    }
    int ex = tsum[tid] - my;
    offs[t4] = ex;
    offs[t4 + 1] = ex + s0;
    offs[t4 + 2] = ex + s0 + s1;
    offs[t4 + 3] = ex + s0 + s1 + s2;
    __syncthreads();
    for (int b = tid; b < 1024; b += 256) cur[b] = offs[b];  // cursors
    __syncthreads();

    // group into sbuf
    for (int k = tid; k < SPLIT_E; k += 256) {
        int b = bbuf[k];
        if (b != 0xFFFF) {
            int slot = atomicAdd(&cur[b], 1);
            sbuf[slot] = ebuf[k];
        }
    }
    __syncthreads();

    // flush one run per thread (contiguous addresses -> L2 line merge)
    for (int b = tid; b < nbuckets; b += 256) {
        int beg = offs[b];
        int len = cur[b] - beg;
        if (len <= 0) continue;
        int g = atomicAdd(&gcnt[b], len);
        if (g >= CAP) continue;
        if (g + len > CAP) len = CAP - g;
        unsigned int* dst = arena + (size_t)b * CAP + g;
        for (int j = 0; j < len; ++j) dst[j] = (unsigned int)sbuf[beg + j];
    }
}

// Per-bucket in-degree -> dinv
__global__ __launch_bounds__(256) void k_dinv(
        const unsigned int* __restrict__ arena, const int* __restrict__ gcnt,
        float* __restrict__ dinv, int n) {
    __shared__ int cnt[BNODES];
    const int b = blockIdx.x, tid = threadIdx.x;
    if (tid < BNODES) cnt[tid] = 0;
    __syncthreads();
    int count = min(gcnt[b], CAP);
    const unsigned int* ent = arena + (size_t)b * CAP;
    for (int p = tid; p < count; p += 256)
        atomicAdd(&cnt[ent[p] >> 20], 1);
    __syncthreads();
    int node = b * BNODES + tid;
    if (tid < BNODES && node < n)
        dinv[node] = rsqrtf((float)(cnt[tid] + 1));
}

// Per-bucket aggregation in LDS; overwrites the consumed arena with agg rows.
__global__ __launch_bounds__(256) void k_agg(
        const int* __restrict__ gcnt, const float* __restrict__ dinv,
        const float* __restrict__ x, char* __restrict__ arena_c, int n) {
    __shared__ float acc[BNODES * NOBS];  // 16 KB
    const int b = blockIdx.x, tid = threadIdx.x;
    for (int i = tid; i < BNODES * NOBS; i += 256) acc[i] = 0.f;
    __syncthreads();

    const unsigned int* ent = (const unsigned int*)(arena_c + (size_t)b * ARENA_B);
    const int count = min(gcnt[b], CAP);
    const int hw = tid >> 5, c = tid & 31;

    int p = hw;
    for (; p + 8 < count; p += 16) {
        unsigned int e0 = ent[p], e1 = ent[p + 8];
        int s0 = e0 & 0xFFFFF, s1 = e1 & 0xFFFFF;
        int d0 = e0 >> 20,     d1 = e1 >> 20;
        float v0 = x[(size_t)s0 * NOBS + c] * dinv[s0];
        float v1 = x[(size_t)s1 * NOBS + c] * dinv[s1];
        atomicAdd(&acc[d0 * NOBS + c], v0);
        atomicAdd(&acc[d1 * NOBS + c], v1);
    }
    if (p < count) {
        unsigned int e0 = ent[p];
        int s0 = e0 & 0xFFFFF, d0 = e0 >> 20;
        atomicAdd(&acc[d0 * NOBS + c], x[(size_t)s0 * NOBS + c] * dinv[s0]);
    }
    __syncthreads();

    // epilogue: agg_row = (acc + dinv_i * x_i) * dinv_i, overwrite arena
    float* aggout = (float*)(arena_c + (size_t)b * ARENA_B);
    for (int i = hw; i < BNODES; i += 8) {
        int node = b * BNODES + i;
        if (node >= n) break;
        float di = dinv[node];
        float v = (acc[i * NOBS + c] + di * x[(size_t)node * NOBS + c]) * di;
        aggout[i * NOBS + c] = v;
    }
}

// Per-node dense epilogue: out = tanh(agg @ W1 + b1) @ W2 + b2.
// agg rows live in the bucket arenas (stride ARENA_B per 128 nodes).
__global__ __launch_bounds__(256) void k_final(
        const char* __restrict__ arena_c, const float* __restrict__ W1,
        const float* __restrict__ b1, const float* __restrict__ W2,
        const float* __restrict__ b2, float* __restrict__ out, int n) {
    __shared__ float sW1T[NMID * NOBS];  // sW1T[j*32+c] = W1[c][j]
    __shared__ float sW2[NMID * NACT];
    __shared__ float sb1[NMID];
    __shared__ float sb2[NACT];
    for (int t = threadIdx.x; t < NMID * NOBS; t += 256) {
        int j = t >> 5, c = t & 31;
        sW1T[t] = W1[c * NMID + j];
    }
    for (int t = threadIdx.x; t < NMID * NACT; t += 256) sW2[t] = W2[t];
    if (threadIdx.x < NMID) sb1[threadIdx.x] = b1[threadIdx.x];
    if (threadIdx.x < NACT) sb2[threadIdx.x] = b2[threadIdx.x];
    __syncthreads();

    int i = blockIdx.x * 256 + threadIdx.x;
    if (i >= n) return;

    const float* arow = (const float*)(arena_c + (size_t)(i >> BSH) * ARENA_B)
                        + (size_t)(i & (BNODES - 1)) * NOBS;
    const float4* a4 = (const float4*)arow;
    float4 A0 = a4[0], A1 = a4[1], A2 = a4[2], A3 = a4[3];
    float4 A4 = a4[4], A5 = a4[5], A6 = a4[6], A7 = a4[7];

    float4 oa = *(const float4*)(sb2);
    float4 ob = *(const float4*)(sb2 + 4);

    for (int j = 0; j < NMID; ++j) {
        const float4* w = (const float4*)(sW1T + j * NOBS);
        float4 w0 = w[0], w1 = w[1], w2 = w[2], w3 = w[3];
        float4 w4 = w[4], w5 = w[5], w6 = w[6], w7 = w[7];
        float ma = sb1[j], mb = 0.f, mc = 0.f, md = 0.f;
        ma = fmaf(A0.x, w0.x, ma); ma = fmaf(A0.y, w0.y, ma);
        ma = fmaf(A0.z, w0.z, ma); ma = fmaf(A0.w, w0.w, ma);
        mb = fmaf(A1.x, w1.x, mb); mb = fmaf(A1.y, w1.y, mb);
        mb = fmaf(A1.z, w1.z, mb); mb = fmaf(A1.w, w1.w, mb);
        mc = fmaf(A2.x, w2.x, mc); mc = fmaf(A2.y, w2.y, mc);
        mc = fmaf(A2.z, w2.z, mc); mc = fmaf(A2.w, w2.w, mc);
        md = fmaf(A3.x, w3.x, md); md = fmaf(A3.y, w3.y, md);
        md = fmaf(A3.z, w3.z, md); md = fmaf(A3.w, w3.w, md);
        ma = fmaf(A4.x, w4.x, ma); ma = fmaf(A4.y, w4.y, ma);
        ma = fmaf(A4.z, w4.z, ma); ma = fmaf(A4.w, w4.w, ma);
        mb = fmaf(A5.x, w5.x, mb); mb = fmaf(A5.y, w5.y, mb);
        mb = fmaf(A5.z, w5.z, mb); mb = fmaf(A5.w, w5.w, mb);
        mc = fmaf(A6.x, w6.x, mc); mc = fmaf(A6.y, w6.y, mc);
        mc = fmaf(A6.z, w6.z, mc); mc = fmaf(A6.w, w6.w, mc);
        md = fmaf(A7.x, w7.x, md); md = fmaf(A7.y, w7.y, md);
        md = fmaf(A7.z, w7.z, md); md = fmaf(A7.w, w7.w, md);
        float m = (ma + mb) + (mc + md);
        float tj = tanhf(m);
        const float4* wp = (const float4*)(sW2 + j * NACT);
        float4 wa = wp[0], wb = wp[1];
        oa.x = fmaf(tj, wa.x, oa.x); oa.y = fmaf(tj, wa.y, oa.y);
        oa.z = fmaf(tj, wa.z, oa.z); oa.w = fmaf(tj, wa.w, oa.w);
        ob.x = fmaf(tj, wb.x, ob.x); ob.y = fmaf(tj, wb.y, ob.y);
        ob.z = fmaf(tj, wb.z, ob.z); ob.w = fmaf(tj, wb.w, ob.w);
    }

    float4* op = (float4*)(out + (size_t)i * NACT);
    op[0] = oa;
    op[1] = ob;
}

extern "C" void kernel_launch(void* const* d_in, const int* in_sizes, int n_in,
                              void* d_out, int out_size, void* d_ws, size_t ws_size,
                              hipStream_t stream) {
    const float* x  = (const float*)d_in[0];
    const int*   ei = (const int*)d_in[1];
    const float* W1 = (const float*)d_in[2];
    const float* b1 = (const float*)d_in[3];
    const float* W2 = (const float*)d_in[4];
    const float* b2 = (const float*)d_in[5];
    float* out = (float*)d_out;

    const int n = in_sizes[0] / NOBS;       // 100000
    const long long e = in_sizes[1] / 2;    // 1600000
    const int B = (n + BNODES - 1) >> BSH;  // 782 buckets (<= 1024 required)

    // ws layout: gcnt int[1024] | arenas B*16KB (entries -> reused as agg) | dinv f32[n]
    char* ws = (char*)d_ws;
    int*   gcnt  = (int*)ws;
    char*  arena = ws + 4096;
    float* dinv  = (float*)(ws + 4096 + (size_t)B * ARENA_B);

    k_zero<<<4, 256, 0, stream>>>(gcnt, 1024);
    int nsb = (int)((e + SPLIT_E - 1) / SPLIT_E);
    k_split<<<nsb, 256, 0, stream>>>(ei, gcnt, (unsigned int*)arena, e, B);
    k_dinv<<<B, 256, 0, stream>>>((const unsigned int*)arena, gcnt, dinv, n);
    k_agg<<<B, 256, 0, stream>>>(gcnt, dinv, x, arena, n);
    k_final<<<(n + 255) / 256, 256, 0, stream>>>(arena, W1, b1, W2, b2, out, n);
}